// Round 4
// baseline (116.989 us; speedup 1.0000x reference)
//
#include <hip/hip_runtime.h>
#include <hip/hip_bf16.h>

#define B_   256
#define T_   2048
#define D_   100
#define U_   50
#define S_   32
#define SEC_ 64

typedef __attribute__((ext_vector_type(8))) short short8;
typedef __attribute__((ext_vector_type(4))) float f32x4;

__device__ __forceinline__ float fast_tanh(float x) {
    // tanh(x) = 1 - 2/(1 + e^{2x}); safe at +-inf
    float e = __expf(2.0f * x);
    return 1.0f - 2.0f * __builtin_amdgcn_rcpf(1.0f + e);
}

__device__ __forceinline__ short f2bf(float f) {
    union { __hip_bfloat16 h; unsigned short u; } cv;
    cv.h = __float2bfloat16(f);  // RNE
    return (short)cv.u;
}

__device__ __forceinline__ short8 pack8(f32x4 a, f32x4 b) {
    short8 r;
    r[0] = f2bf(a[0]); r[1] = f2bf(a[1]); r[2] = f2bf(a[2]); r[3] = f2bf(a[3]);
    r[4] = f2bf(b[0]); r[5] = f2bf(b[1]); r[6] = f2bf(b[2]); r[7] = f2bf(b[3]);
    return r;
}

// wu_proj[b][u] = dot(user_vec[b], wu[u]) + bw[u]
__global__ __launch_bounds__(64) void wu_proj_kernel(
    const float* __restrict__ user_vec, const float* __restrict__ wu,
    const float* __restrict__ bw, float* __restrict__ wup) {
    int b = blockIdx.x;
    int u = threadIdx.x;
    if (u >= U_) return;
    const f32x4* uv4 = reinterpret_cast<const f32x4*>(user_vec + b * D_);
    const f32x4* wu4 = reinterpret_cast<const f32x4*>(wu + u * D_);
    float acc = 0.f;
#pragma unroll
    for (int c = 0; c < D_ / 4; ++c) {
        f32x4 a = uv4[c];
        f32x4 w = wu4[c];
        acc = __builtin_fmaf(a[0], w[0], acc);
        acc = __builtin_fmaf(a[1], w[1], acc);
        acc = __builtin_fmaf(a[2], w[2], acc);
        acc = __builtin_fmaf(a[3], w[3], acc);
    }
    wup[b * U_ + u] = acc + bw[u];
}

// Load one 16-word m-tile of the section into x[7] (per-lane f32x4 chunks).
#define LOADX(X, mm) do {                                                \
    const float* row_ = secbase + (16 * (mm) + li) * D_;                 \
    X[0] = *reinterpret_cast<const f32x4*>(row_ + c0);                   \
    X[1] = *reinterpret_cast<const f32x4*>(row_ + c0 + 16);              \
    X[2] = *reinterpret_cast<const f32x4*>(row_ + c0 + 32);              \
    X[3] = *reinterpret_cast<const f32x4*>(row_ + c0 + 48);              \
    X[4] = *reinterpret_cast<const f32x4*>(row_ + c0 + 64);              \
    X[5] = *reinterpret_cast<const f32x4*>(row_ + c0 + 80);              \
    X[6] = *reinterpret_cast<const f32x4*>(row_ + 96) * mg;              \
} while (0)

// Full per-m-tile compute: proj MFMA, e-scores, p=exp(e-Mb), pooling FMA.
#define COMPUTE_M(X) do {                                                \
    short8 af[4];                                                        \
    af[0] = pack8(X[0], X[1]);                                           \
    af[1] = pack8(X[2], X[3]);                                           \
    af[2] = pack8(X[4], X[5]);                                           \
    af[3] = pack8(X[6], zero4);                                          \
    f32x4 acc[4];                                                        \
    _Pragma("unroll")                                                    \
    for (int n = 0; n < 4; ++n) acc[n] = (f32x4){0.f, 0.f, 0.f, 0.f};    \
    _Pragma("unroll")                                                    \
    for (int ks = 0; ks < 4; ++ks) {                                     \
        _Pragma("unroll")                                                \
        for (int n = 0; n < 4; ++n) {                                    \
            acc[n] = __builtin_amdgcn_mfma_f32_16x16x32_bf16(            \
                af[ks], whb[n * 4 + ks][l], acc[n], 0, 0, 0);            \
        }                                                                \
    }                                                                    \
    float p[4];                                                          \
    _Pragma("unroll")                                                    \
    for (int r = 0; r < 4; ++r) {                                        \
        float t = 0.f;                                                   \
        _Pragma("unroll")                                                \
        for (int n = 0; n < 4; ++n)                                      \
            t = __builtin_fmaf(vwl[n], fast_tanh(acc[n][r] + gl[n]), t); \
        t += __shfl_xor(t, 1);                                           \
        t += __shfl_xor(t, 2);                                           \
        t += __shfl_xor(t, 4);                                           \
        t += __shfl_xor(t, 8);                                           \
        p[r] = __expf(t - Mb);                                           \
    }                                                                    \
    tsum += (p[0] + p[1]) + (p[2] + p[3]);                               \
    const int src = (li >> 2) << 4;                                      \
    const float w0 = __shfl(p[0], src);                                  \
    const float w1 = __shfl(p[1], src);                                  \
    const float w2 = __shfl(p[2], src);                                  \
    const float w3 = __shfl(p[3], src);                                  \
    const float wa = (li & 1) ? w1 : w0;                                 \
    const float wb = (li & 1) ? w3 : w2;                                 \
    const float wgt = (li & 2) ? wb : wa;                                \
    _Pragma("unroll")                                                    \
    for (int j = 0; j < 7; ++j)                                          \
        pool[j] = pool[j] + X[j] * wgt;                                  \
} while (0)

// Block = 4 waves, each wave owns one (b,s) section end-to-end.
// No online rescale: p = exp(e - Mb) with Mb = sum_u |vw[u]| >= max|e|.
__global__ __launch_bounds__(256, 3) void attn_pool_v4(
    const float* __restrict__ sent,     // [B, T, D]
    const float* __restrict__ vw,       // [U]
    const float* __restrict__ wh,       // [U, D]
    const float* __restrict__ wup_all,  // [B, U]
    float* __restrict__ out) {          // [B, S, D]
    __shared__ short8 whb[16][64];      // bf16 B-fragments of wh = 16 KB
    __shared__ float  poolbuf[4][128];  // per-wave store bounce

    const int tid = threadIdx.x;
    const int wid = tid >> 6;
    const int l   = tid & 63;
    const int g   = l >> 4;
    const int li  = l & 15;

    // ---- prologue: wh(f32) -> bf16 B-fragments in LDS ----
#pragma unroll
    for (int j = 0; j < 4; ++j) {
        const int idx = tid + 256 * j;
        const int pli = idx & 15;
        const int pg  = (idx >> 4) & 3;
        const int pks = (idx >> 6) & 3;
        const int pn  = idx >> 8;
        const int u   = 16 * pn + pli;
        const bool uv = (u < U_);
        const int k0  = 32 * pks + 4 * pg;
        const bool v1 = uv && (k0 <= D_ - 4);
        const bool v2 = uv && (k0 + 16 <= D_ - 4);
        const float* rowp = wh + (uv ? u : 0) * D_;
        f32x4 a = *reinterpret_cast<const f32x4*>(rowp + (v1 ? k0 : 0));
        f32x4 b = *reinterpret_cast<const f32x4*>(rowp + (v2 ? k0 + 16 : 0));
        a *= (v1 ? 1.f : 0.f);
        b *= (v2 ? 1.f : 0.f);
        whb[idx >> 6][idx & 63] = pack8(a, b);
    }

    const int b  = blockIdx.x >> 3;
    const int s  = (blockIdx.x & 7) * 4 + wid;
    const float* secbase = sent + ((size_t)b * T_ + (size_t)s * SEC_) * D_;
    const float* wup = wup_all + b * U_;

    // per-lane vw / wu_proj slices (unit u = 16n + li)
    float vwl[4], gl[4];
#pragma unroll
    for (int n = 0; n < 4; ++n) {
        const int uu = 16 * n + li;
        const bool uv = (uu < U_);
        const int uc = uv ? uu : 0;
        const float rv = uv ? 1.f : 0.f;
        vwl[n] = vw[uc] * rv;
        gl[n]  = wup[uc] * rv;
    }
    // Mb = sum_u |vw[u]|  (>= max |e|), replicated across lanes
    float Mb = fabsf(vwl[0]) + fabsf(vwl[1]) + fabsf(vwl[2]) + fabsf(vwl[3]);
    Mb += __shfl_xor(Mb, 1);
    Mb += __shfl_xor(Mb, 2);
    Mb += __shfl_xor(Mb, 4);
    Mb += __shfl_xor(Mb, 8);
    __syncthreads();

    // ---- main: 4 m-tiles, ping-pong loads, no inter-m dependencies ----
    const float mg = (g == 0) ? 1.f : 0.f;  // ks=3 chunk valid only for g==0
    const int c0 = 4 * g;
    const f32x4 zero4 = (f32x4){0.f, 0.f, 0.f, 0.f};

    f32x4 pool[7];
#pragma unroll
    for (int j = 0; j < 7; ++j) pool[j] = zero4;
    float tsum = 0.f;

    f32x4 xA[7], xB[7];
    LOADX(xA, 0);
    LOADX(xB, 1);
    COMPUTE_M(xA);
    LOADX(xA, 2);
    COMPUTE_M(xB);
    LOADX(xB, 3);
    COMPUTE_M(xA);
    COMPUTE_M(xB);

    // ---- denominator: per-g partial -> full section sum ----
    tsum += __shfl_xor(tsum, 16);
    tsum += __shfl_xor(tsum, 32);
    const float inv = 1.0f / tsum;

    // ---- reduce pooling partials over the 16 rows (li lanes) ----
#pragma unroll
    for (int j = 0; j < 7; ++j) {
#pragma unroll
        for (int c = 0; c < 4; ++c) {
            float v = pool[j][c];
            v += __shfl_xor(v, 1);
            v += __shfl_xor(v, 2);
            v += __shfl_xor(v, 4);
            v += __shfl_xor(v, 8);
            pool[j][c] = v;
        }
    }

    // ---- store via tiny per-wave LDS bounce (coalesced global store) ----
    if (li == 0) {
#pragma unroll
        for (int j = 0; j < 6; ++j) {
#pragma unroll
            for (int c = 0; c < 4; ++c) {
                const int k = 32 * (j >> 1) + 16 * (j & 1) + 4 * g + c;
                poolbuf[wid][k] = pool[j][c];
            }
        }
        if (g == 0) {
#pragma unroll
            for (int c = 0; c < 4; ++c) poolbuf[wid][96 + c] = pool[6][c];
        }
    }
    asm volatile("s_waitcnt lgkmcnt(0)" ::: "memory");

    float* po = out + ((size_t)b * S_ + s) * D_;
    po[l] = poolbuf[wid][l] * inv;
    if (l < D_ - SEC_) po[SEC_ + l] = poolbuf[wid][SEC_ + l] * inv;
}

extern "C" void kernel_launch(void* const* d_in, const int* in_sizes, int n_in,
                              void* d_out, int out_size, void* d_ws, size_t ws_size,
                              hipStream_t stream) {
    const float* sent = (const float*)d_in[0];
    const float* uvec = (const float*)d_in[1];
    const float* vw   = (const float*)d_in[2];
    const float* wh   = (const float*)d_in[3];
    const float* wu   = (const float*)d_in[4];
    const float* bw   = (const float*)d_in[5];
    float* out = (float*)d_out;
    float* wup = (float*)d_ws;  // B_*U_ floats

    wu_proj_kernel<<<dim3(B_), dim3(64), 0, stream>>>(uvec, wu, bw, wup);
    attn_pool_v4<<<dim3(B_ * S_ / 4), dim3(256), 0, stream>>>(sent, vw, wh, wup, out);
}

// Round 5
// 60.898 us; speedup vs baseline: 1.9211x; 1.9211x over previous
//
#include <hip/hip_runtime.h>
#include <hip/hip_bf16.h>

#define B_   256
#define T_   2048
#define D_   100
#define U_   50
#define S_   32
#define SEC_ 64

typedef __attribute__((ext_vector_type(8))) short short8;
typedef __attribute__((ext_vector_type(4))) float f32x4;

__device__ __forceinline__ float fast_tanh(float x) {
    // tanh(x) = 1 - 2/(1 + e^{2x}); safe at +-inf
    float e = __expf(2.0f * x);
    return 1.0f - 2.0f * __builtin_amdgcn_rcpf(1.0f + e);
}

__device__ __forceinline__ short f2bf(float f) {
    union { __hip_bfloat16 h; unsigned short u; } cv;
    cv.h = __float2bfloat16(f);  // RNE
    return (short)cv.u;
}

__device__ __forceinline__ short8 pack8(f32x4 a, f32x4 b) {
    short8 r;
    r[0] = f2bf(a[0]); r[1] = f2bf(a[1]); r[2] = f2bf(a[2]); r[3] = f2bf(a[3]);
    r[4] = f2bf(b[0]); r[5] = f2bf(b[1]); r[6] = f2bf(b[2]); r[7] = f2bf(b[3]);
    return r;
}

// wu_proj[b][u] = dot(user_vec[b], wu[u]) + bw[u]
__global__ __launch_bounds__(64) void wu_proj_kernel(
    const float* __restrict__ user_vec, const float* __restrict__ wu,
    const float* __restrict__ bw, float* __restrict__ wup) {
    int b = blockIdx.x;
    int u = threadIdx.x;
    if (u >= U_) return;
    const f32x4* uv4 = reinterpret_cast<const f32x4*>(user_vec + b * D_);
    const f32x4* wu4 = reinterpret_cast<const f32x4*>(wu + u * D_);
    float acc = 0.f;
#pragma unroll
    for (int c = 0; c < D_ / 4; ++c) {
        f32x4 a = uv4[c];
        f32x4 w = wu4[c];
        acc = __builtin_fmaf(a[0], w[0], acc);
        acc = __builtin_fmaf(a[1], w[1], acc);
        acc = __builtin_fmaf(a[2], w[2], acc);
        acc = __builtin_fmaf(a[3], w[3], acc);
    }
    wup[b * U_ + u] = acc + bw[u];
}

// Load one 16-word m-tile of the section into x[7] (per-lane f32x4 chunks).
#define LOADX(X, mm) do {                                                \
    const float* row_ = secbase + (16 * (mm) + li) * D_;                 \
    X[0] = *reinterpret_cast<const f32x4*>(row_ + c0);                   \
    X[1] = *reinterpret_cast<const f32x4*>(row_ + c0 + 16);              \
    X[2] = *reinterpret_cast<const f32x4*>(row_ + c0 + 32);              \
    X[3] = *reinterpret_cast<const f32x4*>(row_ + c0 + 48);              \
    X[4] = *reinterpret_cast<const f32x4*>(row_ + c0 + 64);              \
    X[5] = *reinterpret_cast<const f32x4*>(row_ + c0 + 80);              \
    X[6] = *reinterpret_cast<const f32x4*>(row_ + 96) * mg;              \
} while (0)

// Full per-m-tile compute: proj MFMA, e-scores, p=exp(e-Mb), pooling FMA.
#define COMPUTE_M(X) do {                                                \
    short8 af[4];                                                        \
    af[0] = pack8(X[0], X[1]);                                           \
    af[1] = pack8(X[2], X[3]);                                           \
    af[2] = pack8(X[4], X[5]);                                           \
    af[3] = pack8(X[6], zero4);                                          \
    f32x4 acc[4];                                                        \
    _Pragma("unroll")                                                    \
    for (int n = 0; n < 4; ++n) acc[n] = (f32x4){0.f, 0.f, 0.f, 0.f};    \
    _Pragma("unroll")                                                    \
    for (int ks = 0; ks < 4; ++ks) {                                     \
        _Pragma("unroll")                                                \
        for (int n = 0; n < 4; ++n) {                                    \
            acc[n] = __builtin_amdgcn_mfma_f32_16x16x32_bf16(            \
                af[ks], whb[n * 4 + ks][l], acc[n], 0, 0, 0);            \
        }                                                                \
    }                                                                    \
    float p[4];                                                          \
    _Pragma("unroll")                                                    \
    for (int r = 0; r < 4; ++r) {                                        \
        float t = 0.f;                                                   \
        _Pragma("unroll")                                                \
        for (int n = 0; n < 4; ++n)                                      \
            t = __builtin_fmaf(vwl[n], fast_tanh(acc[n][r] + gl[n]), t); \
        t += __shfl_xor(t, 1);                                           \
        t += __shfl_xor(t, 2);                                           \
        t += __shfl_xor(t, 4);                                           \
        t += __shfl_xor(t, 8);                                           \
        p[r] = __expf(t - Mb);                                           \
    }                                                                    \
    tsum += (p[0] + p[1]) + (p[2] + p[3]);                               \
    const int src = (li >> 2) << 4;                                      \
    const float w0 = __shfl(p[0], src);                                  \
    const float w1 = __shfl(p[1], src);                                  \
    const float w2 = __shfl(p[2], src);                                  \
    const float w3 = __shfl(p[3], src);                                  \
    const float wa = (li & 1) ? w1 : w0;                                 \
    const float wb = (li & 1) ? w3 : w2;                                 \
    const float wgt = (li & 2) ? wb : wa;                                \
    _Pragma("unroll")                                                    \
    for (int j = 0; j < 7; ++j)                                          \
        pool[j] = pool[j] + X[j] * wgt;                                  \
} while (0)

// Block = 4 waves, each wave owns one (b,s) section end-to-end.
// No online rescale: p = exp(e - Mb) with Mb = sum_u |vw[u]| >= max|e|.
__global__ __launch_bounds__(256, 2) void attn_pool_v5(
    const float* __restrict__ sent,     // [B, T, D]
    const float* __restrict__ vw,       // [U]
    const float* __restrict__ wh,       // [U, D]
    const float* __restrict__ wup_all,  // [B, U]
    float* __restrict__ out) {          // [B, S, D]
    __shared__ short8 whb[16][64];      // bf16 B-fragments of wh = 16 KB
    __shared__ float  poolbuf[4][128];  // per-wave store bounce

    const int tid = threadIdx.x;
    const int wid = tid >> 6;
    const int l   = tid & 63;
    const int g   = l >> 4;
    const int li  = l & 15;

    // ---- prologue: wh(f32) -> bf16 B-fragments in LDS ----
#pragma unroll
    for (int j = 0; j < 4; ++j) {
        const int idx = tid + 256 * j;
        const int pli = idx & 15;
        const int pg  = (idx >> 4) & 3;
        const int pks = (idx >> 6) & 3;
        const int pn  = idx >> 8;
        const int u   = 16 * pn + pli;
        const bool uv = (u < U_);
        const int k0  = 32 * pks + 4 * pg;
        const bool v1 = uv && (k0 <= D_ - 4);
        const bool v2 = uv && (k0 + 16 <= D_ - 4);
        const float* rowp = wh + (uv ? u : 0) * D_;
        f32x4 a = *reinterpret_cast<const f32x4*>(rowp + (v1 ? k0 : 0));
        f32x4 b = *reinterpret_cast<const f32x4*>(rowp + (v2 ? k0 + 16 : 0));
        a *= (v1 ? 1.f : 0.f);
        b *= (v2 ? 1.f : 0.f);
        whb[idx >> 6][idx & 63] = pack8(a, b);
    }

    const int b  = blockIdx.x >> 3;
    const int s  = (blockIdx.x & 7) * 4 + wid;
    const float* secbase = sent + ((size_t)b * T_ + (size_t)s * SEC_) * D_;
    const float* wup = wup_all + b * U_;

    // per-lane vw / wu_proj slices (unit u = 16n + li)
    float vwl[4], gl[4];
#pragma unroll
    for (int n = 0; n < 4; ++n) {
        const int uu = 16 * n + li;
        const bool uv = (uu < U_);
        const int uc = uv ? uu : 0;
        const float rv = uv ? 1.f : 0.f;
        vwl[n] = vw[uc] * rv;
        gl[n]  = wup[uc] * rv;
    }
    // Mb = sum_u |vw[u]|  (>= max |e|), replicated across lanes
    float Mb = fabsf(vwl[0]) + fabsf(vwl[1]) + fabsf(vwl[2]) + fabsf(vwl[3]);
    Mb += __shfl_xor(Mb, 1);
    Mb += __shfl_xor(Mb, 2);
    Mb += __shfl_xor(Mb, 4);
    Mb += __shfl_xor(Mb, 8);
    __syncthreads();

    // ---- main: 4 m-tiles, ping-pong loads, no inter-m dependencies ----
    const float mg = (g == 0) ? 1.f : 0.f;  // ks=3 chunk valid only for g==0
    const int c0 = 4 * g;
    const f32x4 zero4 = (f32x4){0.f, 0.f, 0.f, 0.f};

    f32x4 pool[7];
#pragma unroll
    for (int j = 0; j < 7; ++j) pool[j] = zero4;
    float tsum = 0.f;

    f32x4 xA[7], xB[7];
    LOADX(xA, 0);
    LOADX(xB, 1);
    COMPUTE_M(xA);
    LOADX(xA, 2);
    COMPUTE_M(xB);
    LOADX(xB, 3);
    COMPUTE_M(xA);
    COMPUTE_M(xB);

    // ---- denominator: per-g partial -> full section sum ----
    tsum += __shfl_xor(tsum, 16);
    tsum += __shfl_xor(tsum, 32);
    const float inv = 1.0f / tsum;

    // ---- reduce pooling partials over the 16 rows (li lanes) ----
#pragma unroll
    for (int j = 0; j < 7; ++j) {
#pragma unroll
        for (int c = 0; c < 4; ++c) {
            float v = pool[j][c];
            v += __shfl_xor(v, 1);
            v += __shfl_xor(v, 2);
            v += __shfl_xor(v, 4);
            v += __shfl_xor(v, 8);
            pool[j][c] = v;
        }
    }

    // ---- store via tiny per-wave LDS bounce (coalesced global store) ----
    if (li == 0) {
#pragma unroll
        for (int j = 0; j < 6; ++j) {
#pragma unroll
            for (int c = 0; c < 4; ++c) {
                const int k = 32 * (j >> 1) + 16 * (j & 1) + 4 * g + c;
                poolbuf[wid][k] = pool[j][c];
            }
        }
        if (g == 0) {
#pragma unroll
            for (int c = 0; c < 4; ++c) poolbuf[wid][96 + c] = pool[6][c];
        }
    }
    asm volatile("s_waitcnt lgkmcnt(0)" ::: "memory");

    float* po = out + ((size_t)b * S_ + s) * D_;
    po[l] = poolbuf[wid][l] * inv;
    if (l < D_ - SEC_) po[SEC_ + l] = poolbuf[wid][SEC_ + l] * inv;
}

extern "C" void kernel_launch(void* const* d_in, const int* in_sizes, int n_in,
                              void* d_out, int out_size, void* d_ws, size_t ws_size,
                              hipStream_t stream) {
    const float* sent = (const float*)d_in[0];
    const float* uvec = (const float*)d_in[1];
    const float* vw   = (const float*)d_in[2];
    const float* wh   = (const float*)d_in[3];
    const float* wu   = (const float*)d_in[4];
    const float* bw   = (const float*)d_in[5];
    float* out = (float*)d_out;
    float* wup = (float*)d_ws;  // B_*U_ floats

    wu_proj_kernel<<<dim3(B_), dim3(64), 0, stream>>>(uvec, wu, bw, wup);
    attn_pool_v5<<<dim3(B_ * S_ / 4), dim3(256), 0, stream>>>(sent, vw, wh, wup, out);
}

// Round 6
// 52.694 us; speedup vs baseline: 2.2202x; 1.1557x over previous
//
#include <hip/hip_runtime.h>
#include <hip/hip_bf16.h>

#define B_   256
#define T_   2048
#define D_   100
#define U_   50
#define S_   32
#define SEC_ 64

typedef __attribute__((ext_vector_type(8))) short short8;
typedef __attribute__((ext_vector_type(4))) float f32x4;

__device__ __forceinline__ float fast_tanh(float x) {
    // tanh(x) = 1 - 2/(1 + e^{2x}); safe at +-inf
    float e = __expf(2.0f * x);
    return 1.0f - 2.0f * __builtin_amdgcn_rcpf(1.0f + e);
}

__device__ __forceinline__ short f2bf(float f) {
    union { __hip_bfloat16 h; unsigned short u; } cv;
    cv.h = __float2bfloat16(f);  // RNE
    return (short)cv.u;
}

__device__ __forceinline__ short8 pack8(f32x4 a, f32x4 b) {
    short8 r;
    r[0] = f2bf(a[0]); r[1] = f2bf(a[1]); r[2] = f2bf(a[2]); r[3] = f2bf(a[3]);
    r[4] = f2bf(b[0]); r[5] = f2bf(b[1]); r[6] = f2bf(b[2]); r[7] = f2bf(b[3]);
    return r;
}

// wu_proj[b][u] = dot(user_vec[b], wu[u]) + bw[u]
__global__ __launch_bounds__(64) void wu_proj_kernel(
    const float* __restrict__ user_vec, const float* __restrict__ wu,
    const float* __restrict__ bw, float* __restrict__ wup) {
    int b = blockIdx.x;
    int u = threadIdx.x;
    if (u >= U_) return;
    const f32x4* uv4 = reinterpret_cast<const f32x4*>(user_vec + b * D_);
    const f32x4* wu4 = reinterpret_cast<const f32x4*>(wu + u * D_);
    float acc = 0.f;
#pragma unroll
    for (int c = 0; c < D_ / 4; ++c) {
        f32x4 a = uv4[c];
        f32x4 w = wu4[c];
        acc = __builtin_fmaf(a[0], w[0], acc);
        acc = __builtin_fmaf(a[1], w[1], acc);
        acc = __builtin_fmaf(a[2], w[2], acc);
        acc = __builtin_fmaf(a[3], w[3], acc);
    }
    wup[b * U_ + u] = acc + bw[u];
}

// Load one 16-word m-tile of the section into x[7] (per-lane f32x4 chunks).
#define LOADX(X, mm) do {                                                \
    const float* row_ = secbase + (16 * (mm) + li) * D_;                 \
    X[0] = *reinterpret_cast<const f32x4*>(row_ + c0);                   \
    X[1] = *reinterpret_cast<const f32x4*>(row_ + c0 + 16);              \
    X[2] = *reinterpret_cast<const f32x4*>(row_ + c0 + 32);              \
    X[3] = *reinterpret_cast<const f32x4*>(row_ + c0 + 48);              \
    X[4] = *reinterpret_cast<const f32x4*>(row_ + c0 + 64);              \
    X[5] = *reinterpret_cast<const f32x4*>(row_ + c0 + 80);              \
    X[6] = *reinterpret_cast<const f32x4*>(row_ + 96) * mg;              \
} while (0)

// Full per-m-tile compute: proj MFMA, e-scores, p=exp(e-Mb), pooling FMA.
#define COMPUTE_M(X) do {                                                \
    short8 af[4];                                                        \
    af[0] = pack8(X[0], X[1]);                                           \
    af[1] = pack8(X[2], X[3]);                                           \
    af[2] = pack8(X[4], X[5]);                                           \
    af[3] = pack8(X[6], zero4);                                          \
    f32x4 acc[4];                                                        \
    _Pragma("unroll")                                                    \
    for (int n = 0; n < 4; ++n) acc[n] = (f32x4){0.f, 0.f, 0.f, 0.f};    \
    _Pragma("unroll")                                                    \
    for (int ks = 0; ks < 4; ++ks) {                                     \
        _Pragma("unroll")                                                \
        for (int n = 0; n < 4; ++n) {                                    \
            acc[n] = __builtin_amdgcn_mfma_f32_16x16x32_bf16(            \
                af[ks], whb[n * 4 + ks][l], acc[n], 0, 0, 0);            \
        }                                                                \
    }                                                                    \
    float p[4];                                                          \
    _Pragma("unroll")                                                    \
    for (int r = 0; r < 4; ++r) {                                        \
        float t = 0.f;                                                   \
        _Pragma("unroll")                                                \
        for (int n = 0; n < 4; ++n)                                      \
            t = __builtin_fmaf(vwl[n], fast_tanh(acc[n][r] + gl[n]), t); \
        t += __shfl_xor(t, 1);                                           \
        t += __shfl_xor(t, 2);                                           \
        t += __shfl_xor(t, 4);                                           \
        t += __shfl_xor(t, 8);                                           \
        p[r] = __expf(t - Mb);                                           \
    }                                                                    \
    tsum += (p[0] + p[1]) + (p[2] + p[3]);                               \
    const int src = (li >> 2) << 4;                                      \
    const float w0 = __shfl(p[0], src);                                  \
    const float w1 = __shfl(p[1], src);                                  \
    const float w2 = __shfl(p[2], src);                                  \
    const float w3 = __shfl(p[3], src);                                  \
    const float wa = (li & 1) ? w1 : w0;                                 \
    const float wb = (li & 1) ? w3 : w2;                                 \
    const float wgt = (li & 2) ? wb : wa;                                \
    _Pragma("unroll")                                                    \
    for (int j = 0; j < 7; ++j)                                          \
        pool[j] = pool[j] + X[j] * wgt;                                  \
} while (0)

// Block = 4 waves = 2 sections. Wave (p,h): section pair-member p, half h
// (m-tiles 2h, 2h+1). All 14 section loads issue before the prologue barrier.
// Softmax denominator is a pure SUM (Mb bound, no max) -> cross-wave combine
// is one LDS exchange.
__global__ __launch_bounds__(256, 2) void attn_pool_v6(
    const float* __restrict__ sent,     // [B, T, D]
    const float* __restrict__ vw,       // [U]
    const float* __restrict__ wh,       // [U, D]
    const float* __restrict__ wup_all,  // [B, U]
    float* __restrict__ out) {          // [B, S, D]
    __shared__ short8 whb[16][64];      // bf16 B-fragments of wh = 16 KB
    __shared__ float  pbuf[2][2][128];  // per-(pair,half) pool partials = 4 KB
    __shared__ float  tsb[2][2];        // per-(pair,half) denom partials

    const int tid = threadIdx.x;
    const int wid = tid >> 6;
    const int l   = tid & 63;
    const int g   = l >> 4;
    const int li  = l & 15;
    const int p   = wid >> 1;   // section within block
    const int h   = wid & 1;    // half (m-tiles 2h, 2h+1)

    const int b = blockIdx.x >> 4;
    const int s = (blockIdx.x & 15) * 2 + p;
    const float* secbase = sent + ((size_t)b * T_ + (size_t)s * SEC_) * D_;
    const float* wup = wup_all + b * U_;

    // ---- issue ALL section loads first (overlap prologue + barrier) ----
    const float mg = (g == 0) ? 1.f : 0.f;  // ks=3 chunk valid only for g==0
    const int c0 = 4 * g;
    const f32x4 zero4 = (f32x4){0.f, 0.f, 0.f, 0.f};

    f32x4 xA[7], xB[7];
    LOADX(xA, 2 * h);
    LOADX(xB, 2 * h + 1);

    // ---- prologue: wh(f32) -> bf16 B-fragments in LDS ----
#pragma unroll
    for (int j = 0; j < 4; ++j) {
        const int idx = tid + 256 * j;
        const int pli = idx & 15;
        const int pg  = (idx >> 4) & 3;
        const int pks = (idx >> 6) & 3;
        const int pn  = idx >> 8;
        const int u   = 16 * pn + pli;
        const bool uv = (u < U_);
        const int k0  = 32 * pks + 4 * pg;
        const bool v1 = uv && (k0 <= D_ - 4);
        const bool v2 = uv && (k0 + 16 <= D_ - 4);
        const float* rowp = wh + (uv ? u : 0) * D_;
        f32x4 a = *reinterpret_cast<const f32x4*>(rowp + (v1 ? k0 : 0));
        f32x4 bb = *reinterpret_cast<const f32x4*>(rowp + (v2 ? k0 + 16 : 0));
        a  *= (v1 ? 1.f : 0.f);
        bb *= (v2 ? 1.f : 0.f);
        whb[idx >> 6][idx & 63] = pack8(a, bb);
    }

    // per-lane vw / wu_proj slices (unit u = 16n + li)
    float vwl[4], gl[4];
#pragma unroll
    for (int n = 0; n < 4; ++n) {
        const int uu = 16 * n + li;
        const bool uv = (uu < U_);
        const int uc = uv ? uu : 0;
        const float rv = uv ? 1.f : 0.f;
        vwl[n] = vw[uc] * rv;
        gl[n]  = wup[uc] * rv;
    }
    // Mb = sum_u |vw[u]|  (>= max |e|), replicated across lanes
    float Mb = fabsf(vwl[0]) + fabsf(vwl[1]) + fabsf(vwl[2]) + fabsf(vwl[3]);
    Mb += __shfl_xor(Mb, 1);
    Mb += __shfl_xor(Mb, 2);
    Mb += __shfl_xor(Mb, 4);
    Mb += __shfl_xor(Mb, 8);
    __syncthreads();

    // ---- compute both m-tiles ----
    f32x4 pool[7];
#pragma unroll
    for (int j = 0; j < 7; ++j) pool[j] = zero4;
    float tsum = 0.f;

    COMPUTE_M(xA);
    COMPUTE_M(xB);

    // fold g-groups: wave-partial denominator (32 words)
    tsum += __shfl_xor(tsum, 16);
    tsum += __shfl_xor(tsum, 32);

    // ---- reduce pooling partials over the 16 rows (li lanes) ----
#pragma unroll
    for (int j = 0; j < 7; ++j) {
#pragma unroll
        for (int c = 0; c < 4; ++c) {
            float v = pool[j][c];
            v += __shfl_xor(v, 1);
            v += __shfl_xor(v, 2);
            v += __shfl_xor(v, 4);
            v += __shfl_xor(v, 8);
            pool[j][c] = v;
        }
    }

    // ---- cross-wave combine via LDS ----
    if (li == 0) {
#pragma unroll
        for (int j = 0; j < 6; ++j) {
#pragma unroll
            for (int c = 0; c < 4; ++c) {
                const int k = 32 * (j >> 1) + 16 * (j & 1) + 4 * g + c;
                pbuf[p][h][k] = pool[j][c];
            }
        }
        if (g == 0) {
#pragma unroll
            for (int c = 0; c < 4; ++c) pbuf[p][h][96 + c] = pool[6][c];
        }
    }
    if (l == 0) tsb[p][h] = tsum;
    __syncthreads();

    if (h == 0) {
        const float inv = 1.0f / (tsb[p][0] + tsb[p][1]);
        float* po = out + ((size_t)b * S_ + s) * D_;
        po[l] = (pbuf[p][0][l] + pbuf[p][1][l]) * inv;
        if (l < D_ - SEC_)
            po[SEC_ + l] = (pbuf[p][0][SEC_ + l] + pbuf[p][1][SEC_ + l]) * inv;
    }
}

extern "C" void kernel_launch(void* const* d_in, const int* in_sizes, int n_in,
                              void* d_out, int out_size, void* d_ws, size_t ws_size,
                              hipStream_t stream) {
    const float* sent = (const float*)d_in[0];
    const float* uvec = (const float*)d_in[1];
    const float* vw   = (const float*)d_in[2];
    const float* wh   = (const float*)d_in[3];
    const float* wu   = (const float*)d_in[4];
    const float* bw   = (const float*)d_in[5];
    float* out = (float*)d_out;
    float* wup = (float*)d_ws;  // B_*U_ floats

    wu_proj_kernel<<<dim3(B_), dim3(64), 0, stream>>>(uvec, wu, bw, wup);
    attn_pool_v6<<<dim3(B_ * S_ / 2), dim3(256), 0, stream>>>(sent, vw, wh, wup, out);
}

// Round 7
// 52.066 us; speedup vs baseline: 2.2469x; 1.0121x over previous
//
#include <hip/hip_runtime.h>
#include <hip/hip_bf16.h>

#define B_   256
#define T_   2048
#define D_   100
#define U_   50
#define S_   32
#define SEC_ 64

typedef __attribute__((ext_vector_type(8))) short short8;
typedef __attribute__((ext_vector_type(4))) float f32x4;

__device__ __forceinline__ float fast_tanh(float x) {
    // tanh(x) = 1 - 2/(1 + e^{2x}); safe at +-inf
    float e = __expf(2.0f * x);
    return 1.0f - 2.0f * __builtin_amdgcn_rcpf(1.0f + e);
}

__device__ __forceinline__ short f2bf(float f) {
    union { __hip_bfloat16 h; unsigned short u; } cv;
    cv.h = __float2bfloat16(f);  // RNE
    return (short)cv.u;
}

__device__ __forceinline__ short8 pack8(f32x4 a, f32x4 b) {
    short8 r;
    r[0] = f2bf(a[0]); r[1] = f2bf(a[1]); r[2] = f2bf(a[2]); r[3] = f2bf(a[3]);
    r[4] = f2bf(b[0]); r[5] = f2bf(b[1]); r[6] = f2bf(b[2]); r[7] = f2bf(b[3]);
    return r;
}

// wu_proj[b][u] = dot(user_vec[b], wu[u]) + bw[u]
__global__ __launch_bounds__(64) void wu_proj_kernel(
    const float* __restrict__ user_vec, const float* __restrict__ wu,
    const float* __restrict__ bw, float* __restrict__ wup) {
    int b = blockIdx.x;
    int u = threadIdx.x;
    if (u >= U_) return;
    const f32x4* uv4 = reinterpret_cast<const f32x4*>(user_vec + b * D_);
    const f32x4* wu4 = reinterpret_cast<const f32x4*>(wu + u * D_);
    float acc = 0.f;
#pragma unroll
    for (int c = 0; c < D_ / 4; ++c) {
        f32x4 a = uv4[c];
        f32x4 w = wu4[c];
        acc = __builtin_fmaf(a[0], w[0], acc);
        acc = __builtin_fmaf(a[1], w[1], acc);
        acc = __builtin_fmaf(a[2], w[2], acc);
        acc = __builtin_fmaf(a[3], w[3], acc);
    }
    wup[b * U_ + u] = acc + bw[u];
}

// Load one 16-word m-tile of the section into x[7] (per-lane f32x4 chunks).
#define LOADX(X, mm) do {                                                \
    const float* row_ = secbase + (16 * (mm) + li) * D_;                 \
    X[0] = *reinterpret_cast<const f32x4*>(row_ + c0);                   \
    X[1] = *reinterpret_cast<const f32x4*>(row_ + c0 + 16);              \
    X[2] = *reinterpret_cast<const f32x4*>(row_ + c0 + 32);              \
    X[3] = *reinterpret_cast<const f32x4*>(row_ + c0 + 48);              \
    X[4] = *reinterpret_cast<const f32x4*>(row_ + c0 + 64);              \
    X[5] = *reinterpret_cast<const f32x4*>(row_ + c0 + 80);              \
    X[6] = *reinterpret_cast<const f32x4*>(row_ + 96) * mg;              \
} while (0)

// Full per-m-tile compute: proj MFMA, e-scores, p=exp(e-Mb), pooling FMA.
#define COMPUTE_M(X) do {                                                \
    short8 af[4];                                                        \
    af[0] = pack8(X[0], X[1]);                                           \
    af[1] = pack8(X[2], X[3]);                                           \
    af[2] = pack8(X[4], X[5]);                                           \
    af[3] = pack8(X[6], zero4);                                          \
    f32x4 acc[4];                                                        \
    _Pragma("unroll")                                                    \
    for (int n = 0; n < 4; ++n) acc[n] = (f32x4){0.f, 0.f, 0.f, 0.f};    \
    _Pragma("unroll")                                                    \
    for (int ks = 0; ks < 4; ++ks) {                                     \
        _Pragma("unroll")                                                \
        for (int n = 0; n < 4; ++n) {                                    \
            acc[n] = __builtin_amdgcn_mfma_f32_16x16x32_bf16(            \
                af[ks], whb[n * 4 + ks][l], acc[n], 0, 0, 0);            \
        }                                                                \
    }                                                                    \
    float p[4];                                                          \
    _Pragma("unroll")                                                    \
    for (int r = 0; r < 4; ++r) {                                        \
        float t = 0.f;                                                   \
        _Pragma("unroll")                                                \
        for (int n = 0; n < 4; ++n)                                      \
            t = __builtin_fmaf(vwl[n], fast_tanh(acc[n][r] + gl[n]), t); \
        t += __shfl_xor(t, 1);                                           \
        t += __shfl_xor(t, 2);                                           \
        t += __shfl_xor(t, 4);                                           \
        t += __shfl_xor(t, 8);                                           \
        p[r] = __expf(t - Mb);                                           \
    }                                                                    \
    tsum += (p[0] + p[1]) + (p[2] + p[3]);                               \
    const int src = (li >> 2) << 4;                                      \
    const float w0 = __shfl(p[0], src);                                  \
    const float w1 = __shfl(p[1], src);                                  \
    const float w2 = __shfl(p[2], src);                                  \
    const float w3 = __shfl(p[3], src);                                  \
    const float wa = (li & 1) ? w1 : w0;                                 \
    const float wb = (li & 1) ? w3 : w2;                                 \
    const float wgt = (li & 2) ? wb : wa;                                \
    _Pragma("unroll")                                                    \
    for (int j = 0; j < 7; ++j)                                          \
        pool[j] = pool[j] + X[j] * wgt;                                  \
} while (0)

// Block = 4 waves = 2 sections. Wave (p,h): section pair-member p, half h
// (m-tiles 2h, 2h+1). All 14 section loads issue before the prologue barrier.
// Softmax denominator is a pure SUM (Mb bound, no max) -> cross-wave combine
// is one LDS exchange.
// VGPR cap 128 (min 4 waves/EU): live-set peak ~115 (xA+xB+af+acc during A's
// MFMA; pool only live after xA dies) -> no spill, 4 blocks/CU.
__global__ __launch_bounds__(256, 4) void attn_pool_v7(
    const float* __restrict__ sent,     // [B, T, D]
    const float* __restrict__ vw,       // [U]
    const float* __restrict__ wh,       // [U, D]
    const float* __restrict__ wup_all,  // [B, U]
    float* __restrict__ out) {          // [B, S, D]
    __shared__ short8 whb[16][64];      // bf16 B-fragments of wh = 16 KB
    __shared__ float  pbuf[2][2][128];  // per-(pair,half) pool partials = 4 KB
    __shared__ float  tsb[2][2];        // per-(pair,half) denom partials

    const int tid = threadIdx.x;
    const int wid = tid >> 6;
    const int l   = tid & 63;
    const int g   = l >> 4;
    const int li  = l & 15;
    const int p   = wid >> 1;   // section within block
    const int h   = wid & 1;    // half (m-tiles 2h, 2h+1)

    const int b = blockIdx.x >> 4;
    const int s = (blockIdx.x & 15) * 2 + p;
    const float* secbase = sent + ((size_t)b * T_ + (size_t)s * SEC_) * D_;
    const float* wup = wup_all + b * U_;

    // ---- issue ALL section loads first (overlap prologue + barrier) ----
    const float mg = (g == 0) ? 1.f : 0.f;  // ks=3 chunk valid only for g==0
    const int c0 = 4 * g;
    const f32x4 zero4 = (f32x4){0.f, 0.f, 0.f, 0.f};

    f32x4 xA[7], xB[7];
    LOADX(xA, 2 * h);
    LOADX(xB, 2 * h + 1);

    // ---- prologue: wh(f32) -> bf16 B-fragments in LDS ----
#pragma unroll
    for (int j = 0; j < 4; ++j) {
        const int idx = tid + 256 * j;
        const int pli = idx & 15;
        const int pg  = (idx >> 4) & 3;
        const int pks = (idx >> 6) & 3;
        const int pn  = idx >> 8;
        const int u   = 16 * pn + pli;
        const bool uv = (u < U_);
        const int k0  = 32 * pks + 4 * pg;
        const bool v1 = uv && (k0 <= D_ - 4);
        const bool v2 = uv && (k0 + 16 <= D_ - 4);
        const float* rowp = wh + (uv ? u : 0) * D_;
        f32x4 a = *reinterpret_cast<const f32x4*>(rowp + (v1 ? k0 : 0));
        f32x4 bb = *reinterpret_cast<const f32x4*>(rowp + (v2 ? k0 + 16 : 0));
        a  *= (v1 ? 1.f : 0.f);
        bb *= (v2 ? 1.f : 0.f);
        whb[idx >> 6][idx & 63] = pack8(a, bb);
    }

    // per-lane vw / wu_proj slices (unit u = 16n + li)
    float vwl[4], gl[4];
#pragma unroll
    for (int n = 0; n < 4; ++n) {
        const int uu = 16 * n + li;
        const bool uv = (uu < U_);
        const int uc = uv ? uu : 0;
        const float rv = uv ? 1.f : 0.f;
        vwl[n] = vw[uc] * rv;
        gl[n]  = wup[uc] * rv;
    }
    // Mb = sum_u |vw[u]|  (>= max |e|), replicated across lanes
    float Mb = fabsf(vwl[0]) + fabsf(vwl[1]) + fabsf(vwl[2]) + fabsf(vwl[3]);
    Mb += __shfl_xor(Mb, 1);
    Mb += __shfl_xor(Mb, 2);
    Mb += __shfl_xor(Mb, 4);
    Mb += __shfl_xor(Mb, 8);
    __syncthreads();

    // ---- compute both m-tiles ----
    f32x4 pool[7];
#pragma unroll
    for (int j = 0; j < 7; ++j) pool[j] = zero4;
    float tsum = 0.f;

    COMPUTE_M(xA);
    COMPUTE_M(xB);

    // fold g-groups: wave-partial denominator (32 words)
    tsum += __shfl_xor(tsum, 16);
    tsum += __shfl_xor(tsum, 32);

    // ---- reduce pooling partials over the 16 rows (li lanes) ----
#pragma unroll
    for (int j = 0; j < 7; ++j) {
#pragma unroll
        for (int c = 0; c < 4; ++c) {
            float v = pool[j][c];
            v += __shfl_xor(v, 1);
            v += __shfl_xor(v, 2);
            v += __shfl_xor(v, 4);
            v += __shfl_xor(v, 8);
            pool[j][c] = v;
        }
    }

    // ---- cross-wave combine via LDS ----
    if (li == 0) {
#pragma unroll
        for (int j = 0; j < 6; ++j) {
#pragma unroll
            for (int c = 0; c < 4; ++c) {
                const int k = 32 * (j >> 1) + 16 * (j & 1) + 4 * g + c;
                pbuf[p][h][k] = pool[j][c];
            }
        }
        if (g == 0) {
#pragma unroll
            for (int c = 0; c < 4; ++c) pbuf[p][h][96 + c] = pool[6][c];
        }
    }
    if (l == 0) tsb[p][h] = tsum;
    __syncthreads();

    if (h == 0) {
        const float inv = 1.0f / (tsb[p][0] + tsb[p][1]);
        float* po = out + ((size_t)b * S_ + s) * D_;
        po[l] = (pbuf[p][0][l] + pbuf[p][1][l]) * inv;
        if (l < D_ - SEC_)
            po[SEC_ + l] = (pbuf[p][0][SEC_ + l] + pbuf[p][1][SEC_ + l]) * inv;
    }
}

extern "C" void kernel_launch(void* const* d_in, const int* in_sizes, int n_in,
                              void* d_out, int out_size, void* d_ws, size_t ws_size,
                              hipStream_t stream) {
    const float* sent = (const float*)d_in[0];
    const float* uvec = (const float*)d_in[1];
    const float* vw   = (const float*)d_in[2];
    const float* wh   = (const float*)d_in[3];
    const float* wu   = (const float*)d_in[4];
    const float* bw   = (const float*)d_in[5];
    float* out = (float*)d_out;
    float* wup = (float*)d_ws;  // B_*U_ floats

    wu_proj_kernel<<<dim3(B_), dim3(64), 0, stream>>>(uvec, wu, bw, wup);
    attn_pool_v7<<<dim3(B_ * S_ / 2), dim3(256), 0, stream>>>(sent, vw, wh, wup, out);
}